// Round 11
// baseline (32764.310 us; speedup 1.0000x reference)
//
#include <hip/hip_runtime.h>
#include <math.h>

#define BATCH 128
#define TSTEPS 1024
#define INSZ 256
#define HSZ 256
#define MEMN 128

#define NWG_A 64
#define NWG_B 64
#define NWG_C 32
#define NWG 160
#define NTHR 256
#define FSP 16

#define GATE_C 0.40131233988754794f
#define OMG_C  (1.0f - GATE_C)
#define GAMMA_C 0.3f

// ---- per-step state, unique slot per t (WT-produced, cached-read consumed) ----
__device__ float g_hB [(size_t)TSTEPS * BATCH * HSZ];   // h(t)[b][j]
__device__ float g_M  [(size_t)TSTEPS * MEMN * HSZ];    // M(t), slots 1..1023
__device__ float g_Mn [(size_t)TSTEPS * MEMN];
__device__ float g_wwT[(size_t)TSTEPS * MEMN * BATCH];  // wwT(t)[m][b], slots 1..1023
__device__ float g_WTx[256 * 1024];                     // Wih^T gate-interleaved [k][j*4+g]
__device__ float g_WTh[256 * 1024];                     // Whh^T gate-interleaved
__device__ int g_fA[TSTEPS * NWG_A * FSP];
__device__ int g_fB[TSTEPS * NWG_B * FSP];
__device__ int g_fC[TSTEPS * NWG_C * FSP];

__global__ void reset_ctrl_kernel() {
    const int gt = blockIdx.x * 256 + threadIdx.x, gn = gridDim.x * 256;
    for (int i = gt; i < TSTEPS * NWG_A * FSP; i += gn)
        __hip_atomic_store(&g_fA[i], 0, __ATOMIC_RELAXED, __HIP_MEMORY_SCOPE_AGENT);
    for (int i = gt; i < TSTEPS * NWG_B * FSP; i += gn)
        __hip_atomic_store(&g_fB[i], 0, __ATOMIC_RELAXED, __HIP_MEMORY_SCOPE_AGENT);
    for (int i = gt; i < TSTEPS * NWG_C * FSP; i += gn)
        __hip_atomic_store(&g_fC[i], 0, __ATOMIC_RELAXED, __HIP_MEMORY_SCOPE_AGENT);
}

// WT2[k][j*4+g] = W[g*256+j][k], for Wih and Whh
__global__ void transpose_w_kernel(const float* __restrict__ Wih,
                                   const float* __restrict__ Whh) {
    const int bid = blockIdx.x;            // 0..511
    const int p = bid >> 8, k = bid & 255;
    const int j = threadIdx.x;             // 0..255
    const float* src = p ? Whh : Wih;
    float* dst = p ? g_WTh : g_WTx;
#pragma unroll
    for (int g = 0; g < 4; ++g)
        dst[k * 1024 + j * 4 + g] = src[(size_t)(g * 256 + j) * 256 + k];
}

__device__ __forceinline__ float sigf(float x) { return 1.0f / (1.0f + expf(-x)); }
__device__ __forceinline__ void st_wt(float* p, float v) {
    __hip_atomic_store(p, v, __ATOMIC_RELAXED, __HIP_MEMORY_SCOPE_AGENT);
}
__device__ __forceinline__ void st_wt2(float* p, float lo, float hi) {
    unsigned long long pk = (unsigned long long)__float_as_uint(lo) |
                            ((unsigned long long)__float_as_uint(hi) << 32);
    __hip_atomic_store((unsigned long long*)p, pk, __ATOMIC_RELAXED, __HIP_MEMORY_SCOPE_AGENT);
}
__device__ __forceinline__ void st_flag(int* p, int v) {
    __hip_atomic_store(p, v, __ATOMIC_RELAXED, __HIP_MEMORY_SCOPE_AGENT);
}
__device__ __forceinline__ void wait_vm0() { asm volatile("s_waitcnt vmcnt(0)" ::: "memory"); }

__device__ __forceinline__ void wait_flags16(int* f, int n, int want, int lane) {
    int it = 0;
    for (;;) {
        bool ok = true;
        for (int i = lane; i < n; i += 64)
            ok &= (__hip_atomic_load(&f[i * FSP], __ATOMIC_RELAXED, __HIP_MEMORY_SCOPE_AGENT) == want);
        if (__all(ok)) break;
        __builtin_amdgcn_s_sleep(8);
        if (++it > (1 << 20)) break;  // hang valve
    }
}

__global__ void __launch_bounds__(NTHR, 1)
mann_persist(const float* __restrict__ X, const float* __restrict__ bih,
             const float* __restrict__ bhh, float* __restrict__ out) {
    __shared__ __align__(16) float s_raw[33792];  // 132 KB, class-carved
    __shared__ float s_red8[8];
    __shared__ float s_red16[16];
    __shared__ unsigned long long s_redu8[8];

    const int w = blockIdx.x, tid = threadIdx.x;
    const int lane = tid & 63, wv = tid >> 6;

    auto grpsum = [&](float v) -> float {
#pragma unroll
        for (int o = 32; o; o >>= 1) v += __shfl_xor(v, o, 64);
        if (lane == 0) s_red8[wv] = v;
        __syncthreads();
        float r = s_red8[(tid >> 7) * 2] + s_red8[(tid >> 7) * 2 + 1];
        __syncthreads();
        return r;
    };
    auto grpmax = [&](float v) -> float {
#pragma unroll
        for (int o = 32; o; o >>= 1) v = fmaxf(v, __shfl_xor(v, o, 64));
        if (lane == 0) s_red8[wv] = v;
        __syncthreads();
        float r = fmaxf(s_red8[(tid >> 7) * 2], s_red8[(tid >> 7) * 2 + 1]);
        __syncthreads();
        return r;
    };
    auto grpminu = [&](unsigned long long v) -> unsigned long long {
#pragma unroll
        for (int o = 32; o; o >>= 1) {
            unsigned long long o2 = __shfl_xor(v, o, 64);
            v = (o2 < v) ? o2 : v;
        }
        if (lane == 0) s_redu8[wv] = v;
        __syncthreads();
        unsigned long long a = s_redu8[(tid >> 7) * 2], b2 = s_redu8[(tid >> 7) * 2 + 1];
        unsigned long long r = (a < b2) ? a : b2;
        __syncthreads();
        return r;
    };
    auto red256sum4 = [&](float v0, float v1, float v2, float v3, float (&r)[4]) {
#pragma unroll
        for (int o = 32; o; o >>= 1) {
            v0 += __shfl_xor(v0, o, 64);
            v1 += __shfl_xor(v1, o, 64);
            v2 += __shfl_xor(v2, o, 64);
            v3 += __shfl_xor(v3, o, 64);
        }
        if (lane == 0) {
            s_red16[wv * 4 + 0] = v0; s_red16[wv * 4 + 1] = v1;
            s_red16[wv * 4 + 2] = v2; s_red16[wv * 4 + 3] = v3;
        }
        __syncthreads();
#pragma unroll
        for (int k = 0; k < 4; ++k)
            r[k] = (s_red16[0 * 4 + k] + s_red16[1 * 4 + k]) +
                   (s_red16[2 * 4 + k] + s_red16[3 * 4 + k]);
        __syncthreads();
    };

    if (w < NWG_A) {
        // ====== A: batch-partitioned LSTM — ZERO cross-WG handoffs on the chain ======
        float* s_x = s_raw;          // [2][256] x(t)
        float* s_h = s_raw + 512;    // [2][256] h(t-1)
        const int bl = tid >> 7;               // local batch 0/1
        const int bglob = 2 * w + bl;
        const int jc = (tid & 127) * 2;        // this thread's 2 j-columns
        float bias0[4], bias1[4];
#pragma unroll
        for (int g = 0; g < 4; ++g) {
            bias0[g] = bih[g * 256 + jc] + bhh[g * 256 + jc];
            bias1[g] = bih[g * 256 + jc + 1] + bhh[g * 256 + jc + 1];
        }
        // stage x(0); zero h
        {
            const int k2 = (tid & 127) * 2;
            const float2 xv = *(const float2*)&X[((size_t)bglob * TSTEPS + 0) * INSZ + k2];
            *(float2*)&s_x[bl * 256 + k2] = xv;
            s_h[bl * 256 + jc] = 0.f;
            s_h[bl * 256 + jc + 1] = 0.f;
        }
        __syncthreads();
        float c0 = 0.f, c1 = 0.f;
        const float4* wtx = (const float4*)g_WTx;
        const float4* wth = (const float4*)g_WTh;

        for (int t = 0; t < TSTEPS; ++t) {
            float2 xr = make_float2(0.f, 0.f);
            if (t + 1 < TSTEPS) {
                const int k2 = (tid & 127) * 2;
                xr = *(const float2*)&X[((size_t)bglob * TSTEPS + t + 1) * INSZ + k2];
            }
            float4 aX0 = {0,0,0,0}, aX1 = {0,0,0,0}, aH0 = {0,0,0,0}, aH1 = {0,0,0,0};
            const float4* sx4 = (const float4*)&s_x[bl * 256];
            const float4* sh4 = (const float4*)&s_h[bl * 256];
#pragma unroll 2
            for (int k4 = 0; k4 < 64; ++k4) {
                const float4 xk4 = sx4[k4];
                const float4 hk4 = sh4[k4];
#pragma unroll
                for (int u = 0; u < 4; ++u) {
                    const int k = k4 * 4 + u;
                    const float xk = u == 0 ? xk4.x : u == 1 ? xk4.y : u == 2 ? xk4.z : xk4.w;
                    const float hk = u == 0 ? hk4.x : u == 1 ? hk4.y : u == 2 ? hk4.z : hk4.w;
                    const float4 wa = wtx[k * 256 + (jc >> 1) * 2];
                    const float4 wb = wtx[k * 256 + (jc >> 1) * 2 + 1];
                    const float4 va = wth[k * 256 + (jc >> 1) * 2];
                    const float4 vb = wth[k * 256 + (jc >> 1) * 2 + 1];
                    aX0.x += wa.x * xk; aX0.y += wa.y * xk; aX0.z += wa.z * xk; aX0.w += wa.w * xk;
                    aX1.x += wb.x * xk; aX1.y += wb.y * xk; aX1.z += wb.z * xk; aX1.w += wb.w * xk;
                    aH0.x += va.x * hk; aH0.y += va.y * hk; aH0.z += va.z * hk; aH0.w += va.w * hk;
                    aH1.x += vb.x * hk; aH1.y += vb.y * hk; aH1.z += vb.z * hk; aH1.w += vb.w * hk;
                }
            }
            // gates: WT2 component g order matches rows g*256+j
            const float z00 = aX0.x + aH0.x + bias0[0], z01 = aX0.y + aH0.y + bias0[1];
            const float z02 = aX0.z + aH0.z + bias0[2], z03 = aX0.w + aH0.w + bias0[3];
            const float z10 = aX1.x + aH1.x + bias1[0], z11 = aX1.y + aH1.y + bias1[1];
            const float z12 = aX1.z + aH1.z + bias1[2], z13 = aX1.w + aH1.w + bias1[3];
            const float cn0 = sigf(z01) * c0 + sigf(z00) * tanhf(z02);
            const float hn0 = sigf(z03) * tanhf(cn0);
            const float cn1 = sigf(z11) * c1 + sigf(z10) * tanhf(z12);
            const float hn1 = sigf(z13) * tanhf(cn1);
            c0 = cn0; c1 = cn1;
            st_wt2(&g_hB[((size_t)t * BATCH + bglob) * HSZ + jc], hn0, hn1);  // publish
            __syncthreads();              // everyone done reading s_h(t-1)/s_x(t)
            s_h[bl * 256 + jc] = hn0;
            s_h[bl * 256 + jc + 1] = hn1;
            wait_vm0();                   // drains publish + x-prefetch
            *(float2*)&s_x[bl * 256 + (tid & 127) * 2] = xr;
            __syncthreads();
            if (tid == 0) st_flag(&g_fA[((size_t)t * NWG_A + w) * FSP], t + 1);
        }
    } else if (w < NWG_A + NWG_B) {
        // ====== B: read head + output + w_u/w_w ======
        const int bwg = w - NWG_A;
        const int grp = tid >> 7, lm = tid & 127;
        const int bB = bwg * 2 + grp;
        float* s_M = s_raw;             // [128][256]
        float* s_h2 = s_raw + 32768;    // [2][256]
        float* s_wr2 = s_raw + 33280;   // [2][128]
        float wwreg = (lm == 0) ? OMG_C : 0.f;
        float wureg = 0.f;

        for (int t = 0; t < TSTEPS; ++t) {
            if (t > 0) {
                if (wv == 1) wait_flags16(g_fC + (size_t)(t - 1) * NWG_C * FSP, NWG_C, t, lane);
                __syncthreads();
                asm volatile("" ::: "memory");
                float4 mt[32];
                const float4* msrc = (const float4*)&g_M[(size_t)t * MEMN * HSZ];
#pragma unroll
                for (int i = 0; i < 32; ++i) mt[i] = msrc[i * 256 + tid];
                float4* md = (float4*)s_M;
#pragma unroll
                for (int i = 0; i < 32; ++i) md[i * 256 + tid] = mt[i];
            }
            if (wv == 0)
                wait_flags16(g_fA + ((size_t)t * NWG_A + bwg) * FSP, 1, t + 1, lane);
            __syncthreads();
            asm volatile("" ::: "memory");
            s_h2[grp * 256 + lm] = g_hB[((size_t)t * BATCH + bB) * HSZ + lm];
            s_h2[grp * 256 + 128 + lm] = g_hB[((size_t)t * BATCH + bB) * HSZ + 128 + lm];
            __syncthreads();
            const float hv0 = s_h2[grp * 256 + lm], hv1 = s_h2[grp * 256 + lm + 128];
            const float hnorm = sqrtf(grpsum(hv0 * hv0 + hv1 * hv1));
            float sc = 0.f;
            if (t > 0) {
                const float4* mrow = (const float4*)&s_M[(size_t)lm * HSZ];
                const float4* h4 = (const float4*)&s_h2[grp * 256];
                const int sw = lm & 7;
                float a = 0.f;
#pragma unroll 8
                for (int c = 0; c < 64; ++c) {
                    const int ci = c ^ sw;
                    const float4 m4 = mrow[ci], x4 = h4[ci];
                    a += m4.x * x4.x + m4.y * x4.y + m4.z * x4.z + m4.w * x4.w;
                }
                const float mn = g_Mn[(size_t)t * MEMN + lm];
                sc = a / (hnorm * mn + 1e-8f);
            }
            const float mx = grpmax(sc);
            const float ev = expf(sc - mx);
            const float es = grpsum(ev);
            const float wr = ev / es;
            s_wr2[grp * 128 + lm] = wr;
            __syncthreads();
            // ---- chain part first: wu/ww update + publish + flag ----
            const float un = GAMMA_C * wureg + wr + wwreg;
            const float un2 = grpsum(un * un);
            const float us = 1.0f / fmaxf(sqrtf(un2), 1e-12f);
            const float wun = un * us;
            wureg = wun;
            unsigned long long key =
                (((unsigned long long)__float_as_uint(wun)) << 32) | (unsigned)lm;
            const unsigned long long mk = grpminu(key);
            const int amin = (int)(mk & 0xffffffffu);
            const float wwn = GATE_C * wr + ((lm == amin) ? OMG_C : 0.f);
            wwreg = wwn;
            if (t + 1 < TSTEPS)
                st_wt(&g_wwT[((size_t)(t + 1) * MEMN + lm) * BATCH + bB], wwn);
            wait_vm0();
            __syncthreads();
            if (tid == 0) st_flag(&g_fB[((size_t)t * NWG_B + bwg) * FSP], t + 1);
            // ---- off-chain: read vector + out (after flag) ----
            float rd0 = 0.f, rd1 = 0.f;
            if (t > 0) {
#pragma unroll 8
                for (int m = 0; m < 128; ++m) {
                    const float mv = s_M[m * HSZ + tid];
                    rd0 += s_wr2[m] * mv;
                    rd1 += s_wr2[128 + m] * mv;
                }
            }
            float* o0 = out + ((size_t)(bwg * 2) * TSTEPS + t) * 512;
            float* o1 = out + ((size_t)(bwg * 2 + 1) * TSTEPS + t) * 512;
            o0[tid] = s_h2[tid];
            o1[tid] = s_h2[256 + tid];
            o0[256 + tid] = rd0;
            o1[256 + tid] = rd1;
            __syncthreads();
        }
    } else {
        // ====== C: M(t+1) = l2norm(M(t) + ww(t)^T h(t)) ======
        const int cwg = w - NWG_A - NWG_B;
        const int m0 = cwg * 4;
        float* s_hC = s_raw;            // [128][256]
        float* s_wwc = s_raw + 32768;   // [128][4]
        float mreg[4] = {0.f, 0.f, 0.f, 0.f};

        for (int t = 0; t < TSTEPS - 1; ++t) {
            if (wv == 1 && t > 0)
                wait_flags16(g_fB + (size_t)(t - 1) * NWG_B * FSP, NWG_B, t, lane);
            else if (wv == 0)
                wait_flags16(g_fA + (size_t)t * NWG_A * FSP, NWG_A, t + 1, lane);
            __syncthreads();
            asm volatile("" ::: "memory");
            // stage ww(t) -> s_wwc[b][mi]
#pragma unroll
            for (int rep = 0; rep < 2; ++rep) {
                const int idx = rep * 256 + tid;
                const int mi = idx >> 7, b = idx & 127;
                float v;
                if (t > 0) v = g_wwT[((size_t)t * MEMN + m0 + mi) * BATCH + b];
                else v = (m0 + mi == 0) ? OMG_C : 0.f;
                s_wwc[b * 4 + mi] = v;
            }
            // stage h(t) -> s_hC[b][j]
            {
                const float4* hsrc = (const float4*)&g_hB[(size_t)t * BATCH * HSZ];
                float4* hd = (float4*)s_hC;
#pragma unroll
                for (int rep = 0; rep < 32; ++rep) {
                    const int idx = rep * 256 + tid;
                    hd[idx] = hsrc[idx];
                }
            }
            __syncthreads();
            float macc[4];
#pragma unroll
            for (int mi = 0; mi < 4; ++mi) macc[mi] = mreg[mi];
#pragma unroll 8
            for (int b = 0; b < 128; ++b) {
                const float hv = s_hC[b * 256 + tid];
                const float4 w4 = *(const float4*)&s_wwc[b * 4];
                macc[0] += w4.x * hv;
                macc[1] += w4.y * hv;
                macc[2] += w4.z * hv;
                macc[3] += w4.w * hv;
            }
            float nr[4];
            red256sum4(macc[0] * macc[0], macc[1] * macc[1],
                       macc[2] * macc[2], macc[3] * macc[3], nr);
#pragma unroll
            for (int mi = 0; mi < 4; ++mi) {
                const float nrm = sqrtf(nr[mi]);
                const float scale = 1.0f / fmaxf(nrm, 1e-12f);
                const float vo = macc[mi] * scale;
                mreg[mi] = vo;
                st_wt(&g_M[((size_t)(t + 1) * MEMN + m0 + mi) * HSZ + tid], vo);
                if (tid == 0) st_wt(&g_Mn[(size_t)(t + 1) * MEMN + m0 + mi], nrm * scale);
            }
            wait_vm0();
            __syncthreads();
            if (tid == 0) st_flag(&g_fC[((size_t)t * NWG_C + cwg) * FSP], t + 1);
        }
    }
}

extern "C" void kernel_launch(void* const* d_in, const int* in_sizes, int n_in,
                              void* d_out, int out_size, void* d_ws, size_t ws_size,
                              hipStream_t stream) {
    const float* X   = (const float*)d_in[0];
    const float* Wih = (const float*)d_in[1];
    const float* Whh = (const float*)d_in[2];
    const float* bih = (const float*)d_in[3];
    const float* bhh = (const float*)d_in[4];
    float* out = (float*)d_out;
    (void)in_sizes; (void)n_in; (void)out_size; (void)d_ws; (void)ws_size;

    hipLaunchKernelGGL(reset_ctrl_kernel, dim3(512), dim3(256), 0, stream);
    hipLaunchKernelGGL(transpose_w_kernel, dim3(512), dim3(256), 0, stream, Wih, Whh);
    hipLaunchKernelGGL(mann_persist, dim3(NWG), dim3(NTHR), 0, stream,
                       X, bih, bhh, out);
}

// Round 12
// 25243.288 us; speedup vs baseline: 1.2979x; 1.2979x over previous
//
#include <hip/hip_runtime.h>
#include <math.h>

#define BATCH 128
#define TSTEPS 1024
#define INSZ 256
#define HSZ 256
#define MEMN 128

#define NWG_A 64
#define NWG_B 64
#define NWG_C 32
#define NWG 160
#define NTHR 256
#define FSP 16   // flag spread (ints) -> 64B apart

#define GATE_C 0.40131233988754794f
#define OMG_C  (1.0f - GATE_C)
#define GAMMA_C 0.3f

// ---- per-step state, unique slot per t (WT-produced, cached-read consumed) ----
__device__ float g_zx [(size_t)TSTEPS * 4 * HSZ * BATCH];  // zx(t)[g][j][b]
__device__ float g_hB [(size_t)TSTEPS * BATCH * HSZ];      // h(t)[b][j]
__device__ float g_hT [(size_t)TSTEPS * HSZ * BATCH];      // hT(t)[j][b]
__device__ float g_M  [(size_t)TSTEPS * MEMN * HSZ];       // M(t), slots 1..1023
__device__ float g_Mn [(size_t)TSTEPS * MEMN];
__device__ float g_wwT[(size_t)TSTEPS * MEMN * BATCH];     // wwT(t)[m][b], slots 1..1023
__device__ int g_fA[TSTEPS * NWG_A * FSP];
__device__ int g_fB[TSTEPS * NWG_B * FSP];
__device__ int g_fC[TSTEPS * NWG_C * FSP];

__global__ void reset_ctrl_kernel() {
    const int gt = blockIdx.x * 256 + threadIdx.x, gn = gridDim.x * 256;
    for (int i = gt; i < TSTEPS * NWG_A * FSP; i += gn)
        __hip_atomic_store(&g_fA[i], 0, __ATOMIC_RELAXED, __HIP_MEMORY_SCOPE_AGENT);
    for (int i = gt; i < TSTEPS * NWG_B * FSP; i += gn)
        __hip_atomic_store(&g_fB[i], 0, __ATOMIC_RELAXED, __HIP_MEMORY_SCOPE_AGENT);
    for (int i = gt; i < TSTEPS * NWG_C * FSP; i += gn)
        __hip_atomic_store(&g_fC[i], 0, __ATOMIC_RELAXED, __HIP_MEMORY_SCOPE_AGENT);
}

__device__ __forceinline__ float sigf(float x) { return 1.0f / (1.0f + expf(-x)); }
__device__ __forceinline__ void st_wt(float* p, float v) {
    __hip_atomic_store(p, v, __ATOMIC_RELAXED, __HIP_MEMORY_SCOPE_AGENT);
}
__device__ __forceinline__ void st_wt2(float* p, float lo, float hi) {
    unsigned long long pk = (unsigned long long)__float_as_uint(lo) |
                            ((unsigned long long)__float_as_uint(hi) << 32);
    __hip_atomic_store((unsigned long long*)p, pk, __ATOMIC_RELAXED, __HIP_MEMORY_SCOPE_AGENT);
}
// flag publication via RMW: executes AT the MALL -> immediately visible to pollers
__device__ __forceinline__ void st_flag(int* p, int v) {
    (void)__hip_atomic_exchange(p, v, __ATOMIC_RELAXED, __HIP_MEMORY_SCOPE_AGENT);
}
__device__ __forceinline__ void wait_vm0() { asm volatile("s_waitcnt vmcnt(0)" ::: "memory"); }

// wave scan over spread flags
__device__ __forceinline__ void wait_flags16(int* f, int n, int want, int lane) {
    int it = 0;
    for (;;) {
        bool ok = true;
        for (int i = lane; i < n; i += 64)
            ok &= (__hip_atomic_load(&f[i * FSP], __ATOMIC_RELAXED, __HIP_MEMORY_SCOPE_AGENT) == want);
        if (__all(ok)) break;
        __builtin_amdgcn_s_sleep(8);
        if (++it > (1 << 20)) break;  // hang valve
    }
}

// ================= zx precompute (R9/R10-verified) =================
__global__ void __launch_bounds__(NTHR, 2)
pre_kernel(const float* __restrict__ X, const float* __restrict__ Wih,
           const float* __restrict__ bih, const float* __restrict__ bhh) {
    __shared__ float4 p_x[4096];
    const int w = blockIdx.x, tid = threadIdx.x;
    const int t = w >> 1, half = w & 1;
#pragma unroll
    for (int rep = 0; rep < 16; ++rep) {
        const int idx = rep * 256 + tid;
        const int bl = idx >> 6, c = idx & 63;
        p_x[bl * 64 + (c ^ bl)] =
            *(const float4*)&X[((size_t)(half * 64 + bl) * TSTEPS + t) * INSZ + c * 4];
    }
    __syncthreads();
    const int bl = tid & 63, hf2 = tid >> 6;
    const int b = half * 64 + bl;
    const float4* wih4 = (const float4*)Wih;
    for (int jb4 = 0; jb4 < 16; ++jb4) {
        float a16[16];
#pragma unroll
        for (int i = 0; i < 16; ++i) a16[i] = 0.f;
#pragma unroll 4
        for (int c = 0; c < 64; ++c) {
            const float4 xv = p_x[bl * 64 + (c ^ bl)];
#pragma unroll
            for (int g = 0; g < 4; ++g)
#pragma unroll
                for (int j4 = 0; j4 < 4; ++j4) {
                    const int row = g * HSZ + hf2 * 64 + jb4 * 4 + j4;
                    const float4 wv4 = wih4[(size_t)row * 64 + c];
                    a16[g * 4 + j4] += wv4.x * xv.x + wv4.y * xv.y + wv4.z * xv.z + wv4.w * xv.w;
                }
        }
#pragma unroll
        for (int g = 0; g < 4; ++g)
#pragma unroll
            for (int j4 = 0; j4 < 4; ++j4) {
                const int j = hf2 * 64 + jb4 * 4 + j4;
                const int row = g * HSZ + j;
                g_zx[(((size_t)t * 4 + g) * HSZ + j) * BATCH + b] =
                    a16[g * 4 + j4] + bih[row] + bhh[row];
            }
    }
}

// ================= persistent A/B/C =================
__global__ void __launch_bounds__(NTHR, 1)
mann_persist(const float* __restrict__ Whh, float* __restrict__ out) {
    __shared__ float4 s_big[8192];   // A: s_h4 (64KB used); B: s_M (128 KB)
    __shared__ float s_aux[1024];    // B: s_h2+s_wr2; C: s_wwc
    __shared__ float s_tr[512];      // A: publish staging [8 j][64 b]
    __shared__ float s_red8[8];
    __shared__ float s_red16[16];
    __shared__ unsigned long long s_redu8[8];

    const int w = blockIdx.x, tid = threadIdx.x;
    const int lane = tid & 63, wv = tid >> 6;

    auto grpsum = [&](float v) -> float {
#pragma unroll
        for (int o = 32; o; o >>= 1) v += __shfl_xor(v, o, 64);
        if (lane == 0) s_red8[wv] = v;
        __syncthreads();
        float r = s_red8[(tid >> 7) * 2] + s_red8[(tid >> 7) * 2 + 1];
        __syncthreads();
        return r;
    };
    auto grpmax = [&](float v) -> float {
#pragma unroll
        for (int o = 32; o; o >>= 1) v = fmaxf(v, __shfl_xor(v, o, 64));
        if (lane == 0) s_red8[wv] = v;
        __syncthreads();
        float r = fmaxf(s_red8[(tid >> 7) * 2], s_red8[(tid >> 7) * 2 + 1]);
        __syncthreads();
        return r;
    };
    auto grpminu = [&](unsigned long long v) -> unsigned long long {
#pragma unroll
        for (int o = 32; o; o >>= 1) {
            unsigned long long o2 = __shfl_xor(v, o, 64);
            v = (o2 < v) ? o2 : v;
        }
        if (lane == 0) s_redu8[wv] = v;
        __syncthreads();
        unsigned long long a = s_redu8[(tid >> 7) * 2], b2 = s_redu8[(tid >> 7) * 2 + 1];
        unsigned long long r = (a < b2) ? a : b2;
        __syncthreads();
        return r;
    };
    auto red256sum4 = [&](float v0, float v1, float v2, float v3, float (&r)[4]) {
#pragma unroll
        for (int o = 32; o; o >>= 1) {
            v0 += __shfl_xor(v0, o, 64);
            v1 += __shfl_xor(v1, o, 64);
            v2 += __shfl_xor(v2, o, 64);
            v3 += __shfl_xor(v3, o, 64);
        }
        if (lane == 0) {
            s_red16[wv * 4 + 0] = v0; s_red16[wv * 4 + 1] = v1;
            s_red16[wv * 4 + 2] = v2; s_red16[wv * 4 + 3] = v3;
        }
        __syncthreads();
#pragma unroll
        for (int k = 0; k < 4; ++k)
            r[k] = (s_red16[0 * 4 + k] + s_red16[1 * 4 + k]) +
                   (s_red16[2 * 4 + k] + s_red16[3 * 4 + k]);
        __syncthreads();
    };

    if (w < NWG_A) {
        // ====== A: h(t) = LSTM(zx(t), h(t-1)); j-partitioned, half-local gather ======
        const int bb = w >> 5, jb = w & 31;
        const int J = jb * 8;
        const int jA = J + wv * 2;
        const int bglob = bb * 64 + lane;
        float4* s_h4 = s_big;
        float creg0 = 0.f, creg1 = 0.f;
        float zxr[8];
#pragma unroll
        for (int g = 0; g < 4; ++g)
#pragma unroll
            for (int jj = 0; jj < 2; ++jj)
                zxr[g * 2 + jj] = g_zx[((size_t)(0 * 4 + g) * HSZ + jA + jj) * BATCH + bglob];

        for (int t = 0; t < TSTEPS; ++t) {
            if (t > 0) {
                if (wv == 0)
                    wait_flags16(g_fA + ((size_t)(t - 1) * NWG_A + bb * 32) * FSP, 32, t, lane);
                __syncthreads();
                asm volatile("" ::: "memory");
#pragma unroll
                for (int rep = 0; rep < 16; ++rep) {
                    const int id = rep * 256 + tid, b = id >> 6, c = id & 63;
                    s_h4[b * 64 + (c ^ (b & 7))] =
                        *(const float4*)&g_hB[((size_t)(t - 1) * BATCH + bb * 64 + b) * HSZ + c * 4];
                }
                __syncthreads();
            }
            float acc[8] = {0.f, 0.f, 0.f, 0.f, 0.f, 0.f, 0.f, 0.f};
            if (t > 0) {
#pragma unroll 8
                for (int c = 0; c < 64; ++c) {
                    const float4 xv = s_h4[lane * 64 + (c ^ (lane & 7))];
#pragma unroll
                    for (int g = 0; g < 4; ++g)
#pragma unroll
                        for (int jj = 0; jj < 2; ++jj) {
                            const float4 w4 =
                                *(const float4*)&Whh[(size_t)(g * HSZ + jA + jj) * HSZ + c * 4];
                            acc[g * 2 + jj] += w4.x * xv.x + w4.y * xv.y + w4.z * xv.z + w4.w * xv.w;
                        }
                }
            }
#pragma unroll
            for (int jj = 0; jj < 2; ++jj) {
                const float z0 = zxr[0 * 2 + jj] + acc[0 * 2 + jj];
                const float z1 = zxr[1 * 2 + jj] + acc[1 * 2 + jj];
                const float z2 = zxr[2 * 2 + jj] + acc[2 * 2 + jj];
                const float z3 = zxr[3 * 2 + jj] + acc[3 * 2 + jj];
                float cr = jj ? creg1 : creg0;
                const float cn = sigf(z1) * cr + sigf(z0) * tanhf(z2);
                const float hn = sigf(z3) * tanhf(cn);
                if (jj) creg1 = cn; else creg0 = cn;
                s_tr[(wv * 2 + jj) * 64 + lane] = hn;
            }
            __syncthreads();
            if (tid < 128) {
                {   // b-major publish
                    const int b = tid >> 1, q = tid & 1;
                    const float v0 = s_tr[(q * 4 + 0) * 64 + b];
                    const float v1 = s_tr[(q * 4 + 1) * 64 + b];
                    const float v2 = s_tr[(q * 4 + 2) * 64 + b];
                    const float v3 = s_tr[(q * 4 + 3) * 64 + b];
                    float* dst = &g_hB[((size_t)t * BATCH + bb * 64 + b) * HSZ + J + q * 4];
                    st_wt2(dst, v0, v1);
                    st_wt2(dst + 2, v2, v3);
                }
                {   // j-major publish
                    const int j = tid >> 4, c = tid & 15;
                    const float v0 = s_tr[j * 64 + c * 4 + 0];
                    const float v1 = s_tr[j * 64 + c * 4 + 1];
                    const float v2 = s_tr[j * 64 + c * 4 + 2];
                    const float v3 = s_tr[j * 64 + c * 4 + 3];
                    float* dst = &g_hT[((size_t)t * HSZ + J + j) * BATCH + bb * 64 + c * 4];
                    st_wt2(dst, v0, v1);
                    st_wt2(dst + 2, v2, v3);
                }
            }
            wait_vm0();
            __syncthreads();
            if (tid == 0) st_flag(&g_fA[((size_t)t * NWG_A + w) * FSP], t + 1);
            if (t + 1 < TSTEPS) {
#pragma unroll
                for (int g = 0; g < 4; ++g)
#pragma unroll
                    for (int jj = 0; jj < 2; ++jj)
                        zxr[g * 2 + jj] =
                            g_zx[((size_t)((t + 1) * 4 + g) * HSZ + jA + jj) * BATCH + bglob];
            }
        }
    } else if (w < NWG_A + NWG_B) {
        // ====== B: read head + output + w_u/w_w; chain publishes BEFORE off-chain work ======
        const int bwg = w - NWG_A;
        const int halfB = bwg >> 5;
        const int grp = tid >> 7, lm = tid & 127;
        const int bB = bwg * 2 + grp;
        float* s_M = (float*)s_big;
        float* s_h2 = s_aux;
        float* s_wr2 = s_aux + 512;
        float wwreg = (lm == 0) ? OMG_C : 0.f;
        float wureg = 0.f;

        for (int t = 0; t < TSTEPS; ++t) {
            if (t > 0) {
                if (wv == 1) wait_flags16(g_fC + (size_t)(t - 1) * NWG_C * FSP, NWG_C, t, lane);
                __syncthreads();
                asm volatile("" ::: "memory");
                float4 mt[32];
                const float4* msrc = (const float4*)&g_M[(size_t)t * MEMN * HSZ];
#pragma unroll
                for (int i = 0; i < 32; ++i) mt[i] = msrc[i * 256 + tid];
                float4* md = (float4*)s_M;
#pragma unroll
                for (int i = 0; i < 32; ++i) md[i * 256 + tid] = mt[i];
            }
            if (wv == 0)
                wait_flags16(g_fA + ((size_t)t * NWG_A + halfB * 32) * FSP, 32, t + 1, lane);
            __syncthreads();
            asm volatile("" ::: "memory");
            s_h2[grp * 256 + lm] = g_hB[((size_t)t * BATCH + bB) * HSZ + lm];
            s_h2[grp * 256 + 128 + lm] = g_hB[((size_t)t * BATCH + bB) * HSZ + 128 + lm];
            __syncthreads();
            const float hv0 = s_h2[grp * 256 + lm], hv1 = s_h2[grp * 256 + lm + 128];
            const float hnorm = sqrtf(grpsum(hv0 * hv0 + hv1 * hv1));
            float sc = 0.f;
            if (t > 0) {
                const float4* mrow = (const float4*)&s_M[(size_t)lm * HSZ];
                const float4* h4 = (const float4*)&s_h2[grp * 256];
                const int sw = lm & 7;
                float a = 0.f;
#pragma unroll 8
                for (int c = 0; c < 64; ++c) {
                    const int ci = c ^ sw;
                    const float4 m4 = mrow[ci], x4 = h4[ci];
                    a += m4.x * x4.x + m4.y * x4.y + m4.z * x4.z + m4.w * x4.w;
                }
                const float mn = g_Mn[(size_t)t * MEMN + lm];
                sc = a / (hnorm * mn + 1e-8f);
            }
            const float mx = grpmax(sc);
            const float ev = expf(sc - mx);
            const float es = grpsum(ev);
            const float wr = ev / es;
            s_wr2[grp * 128 + lm] = wr;
            __syncthreads();
            // ---- chain-critical: wu/ww update + publish + flag ----
            const float un = GAMMA_C * wureg + wr + wwreg;
            const float un2 = grpsum(un * un);
            const float us = 1.0f / fmaxf(sqrtf(un2), 1e-12f);
            const float wun = un * us;
            wureg = wun;
            unsigned long long key =
                (((unsigned long long)__float_as_uint(wun)) << 32) | (unsigned)lm;
            const unsigned long long mk = grpminu(key);
            const int amin = (int)(mk & 0xffffffffu);
            const float wwn = GATE_C * wr + ((lm == amin) ? OMG_C : 0.f);
            wwreg = wwn;
            if (t + 1 < TSTEPS)
                st_wt(&g_wwT[((size_t)(t + 1) * MEMN + lm) * BATCH + bB], wwn);
            wait_vm0();
            __syncthreads();
            if (tid == 0) st_flag(&g_fB[((size_t)t * NWG_B + bwg) * FSP], t + 1);
            // ---- off-chain: read vector + out (drains during next step's waits) ----
            float rd0 = 0.f, rd1 = 0.f;
            if (t > 0) {
#pragma unroll 8
                for (int m = 0; m < 128; ++m) {
                    const float mv = s_M[m * HSZ + tid];
                    rd0 += s_wr2[m] * mv;
                    rd1 += s_wr2[128 + m] * mv;
                }
            }
            float* o0 = out + ((size_t)(bwg * 2) * TSTEPS + t) * 512;
            float* o1 = out + ((size_t)(bwg * 2 + 1) * TSTEPS + t) * 512;
            o0[tid] = s_h2[tid];
            o1[tid] = s_h2[256 + tid];
            o0[256 + tid] = rd0;
            o1[256 + tid] = rd1;
            __syncthreads();  // protect s_M/s_wr2/s_h2 before next iteration's staging
        }
    } else {
        // ====== C: M(t+1) = l2norm(M(t) + ww(t)^T h(t)) ======
        const int cwg = w - NWG_A - NWG_B;
        const int m0 = cwg * 4;
        float* s_wwc = s_aux;  // [4][128]
        float mreg[4] = {0.f, 0.f, 0.f, 0.f};

        for (int t = 0; t < TSTEPS - 1; ++t) {
            if (wv == 1 && t > 0)
                wait_flags16(g_fB + (size_t)(t - 1) * NWG_B * FSP, NWG_B, t, lane);
            __syncthreads();
            asm volatile("" ::: "memory");
            {
                const int e0 = tid, e1 = tid + 256;
                float v0, v1;
                if (t > 0) {
                    v0 = g_wwT[((size_t)t * MEMN + m0 + (e0 >> 7)) * BATCH + (e0 & 127)];
                    v1 = g_wwT[((size_t)t * MEMN + m0 + (e1 >> 7)) * BATCH + (e1 & 127)];
                } else {
                    v0 = (m0 + (e0 >> 7) == 0) ? OMG_C : 0.f;
                    v1 = (m0 + (e1 >> 7) == 0) ? OMG_C : 0.f;
                }
                s_wwc[(e0 >> 7) * 128 + (e0 & 127)] = v0;
                s_wwc[(e1 >> 7) * 128 + (e1 & 127)] = v1;
            }
            if (wv == 0) wait_flags16(g_fA + (size_t)t * NWG_A * FSP, NWG_A, t + 1, lane);
            __syncthreads();
            asm volatile("" ::: "memory");
            float4 hb[32];
            const float4* ht4 = (const float4*)&g_hT[((size_t)t * HSZ + tid) * BATCH];
#pragma unroll
            for (int q = 0; q < 32; ++q) hb[q] = ht4[q];
            float macc[4];
#pragma unroll
            for (int mi = 0; mi < 4; ++mi) macc[mi] = mreg[mi];
#pragma unroll
            for (int b4 = 0; b4 < 32; ++b4) {
                const float4 hv4 = hb[b4];
#pragma unroll
                for (int mi = 0; mi < 4; ++mi) {
                    const float* wc = &s_wwc[mi * 128 + b4 * 4];
                    macc[mi] += wc[0] * hv4.x + wc[1] * hv4.y + wc[2] * hv4.z + wc[3] * hv4.w;
                }
            }
            float nr[4];
            red256sum4(macc[0] * macc[0], macc[1] * macc[1],
                       macc[2] * macc[2], macc[3] * macc[3], nr);
#pragma unroll
            for (int mi = 0; mi < 4; ++mi) {
                const float nrm = sqrtf(nr[mi]);
                const float scale = 1.0f / fmaxf(nrm, 1e-12f);
                const float vo = macc[mi] * scale;
                mreg[mi] = vo;
                st_wt(&g_M[((size_t)(t + 1) * MEMN + m0 + mi) * HSZ + tid], vo);
                if (tid == 0) st_wt(&g_Mn[(size_t)(t + 1) * MEMN + m0 + mi], nrm * scale);
            }
            wait_vm0();
            __syncthreads();
            if (tid == 0) st_flag(&g_fC[((size_t)t * NWG_C + cwg) * FSP], t + 1);
        }
    }
}

extern "C" void kernel_launch(void* const* d_in, const int* in_sizes, int n_in,
                              void* d_out, int out_size, void* d_ws, size_t ws_size,
                              hipStream_t stream) {
    const float* X   = (const float*)d_in[0];
    const float* Wih = (const float*)d_in[1];
    const float* Whh = (const float*)d_in[2];
    const float* bih = (const float*)d_in[3];
    const float* bhh = (const float*)d_in[4];
    float* out = (float*)d_out;
    (void)in_sizes; (void)n_in; (void)out_size; (void)d_ws; (void)ws_size;

    hipLaunchKernelGGL(reset_ctrl_kernel, dim3(1024), dim3(256), 0, stream);
    hipLaunchKernelGGL(pre_kernel, dim3(2048), dim3(NTHR), 0, stream, X, Wih, bih, bhh);
    hipLaunchKernelGGL(mann_persist, dim3(NWG), dim3(NTHR), 0, stream, Whh, out);
}

// Round 13
// 25230.614 us; speedup vs baseline: 1.2986x; 1.0005x over previous
//
#include <hip/hip_runtime.h>
#include <math.h>

#define BATCH 128
#define TSTEPS 1024
#define INSZ 256
#define HSZ 256
#define MEMN 128

#define NWG_A 64
#define NWG_B 64
#define NWG_C 32
#define NWG 160
#define NWG_TOT 256
#define NTHR 256
#define FSP 16   // flag spread (ints) -> 64B apart

#define GATE_C 0.40131233988754794f
#define OMG_C  (1.0f - GATE_C)
#define GAMMA_C 0.3f

// ---- per-step state, unique slot per t (WT-produced, cached-read consumed) ----
__device__ float g_zx [(size_t)TSTEPS * 4 * HSZ * BATCH];  // zx(t)[g][j][b]
__device__ float g_hB [(size_t)TSTEPS * BATCH * HSZ];      // h(t)[b][j]
__device__ float g_hT [(size_t)TSTEPS * HSZ * BATCH];      // hT(t)[j][b]
__device__ float g_M  [(size_t)TSTEPS * MEMN * HSZ];       // M(t), slots 1..1023
__device__ float g_Mn [(size_t)TSTEPS * MEMN];
__device__ float g_wwT[(size_t)TSTEPS * MEMN * BATCH];     // wwT(t)[m][b], slots 1..1023
__device__ int g_fA[TSTEPS * NWG_A * FSP];
__device__ int g_fB[TSTEPS * NWG_B * FSP];
__device__ int g_fC[TSTEPS * NWG_C * FSP];

__global__ void reset_ctrl_kernel() {
    const int gt = blockIdx.x * 256 + threadIdx.x, gn = gridDim.x * 256;
    for (int i = gt; i < TSTEPS * NWG_A * FSP; i += gn)
        __hip_atomic_store(&g_fA[i], 0, __ATOMIC_RELAXED, __HIP_MEMORY_SCOPE_AGENT);
    for (int i = gt; i < TSTEPS * NWG_B * FSP; i += gn)
        __hip_atomic_store(&g_fB[i], 0, __ATOMIC_RELAXED, __HIP_MEMORY_SCOPE_AGENT);
    for (int i = gt; i < TSTEPS * NWG_C * FSP; i += gn)
        __hip_atomic_store(&g_fC[i], 0, __ATOMIC_RELAXED, __HIP_MEMORY_SCOPE_AGENT);
}

__device__ __forceinline__ float sigf(float x) { return 1.0f / (1.0f + expf(-x)); }
__device__ __forceinline__ void st_wt(float* p, float v) {
    __hip_atomic_store(p, v, __ATOMIC_RELAXED, __HIP_MEMORY_SCOPE_AGENT);
}
__device__ __forceinline__ void st_wt2(float* p, float lo, float hi) {
    unsigned long long pk = (unsigned long long)__float_as_uint(lo) |
                            ((unsigned long long)__float_as_uint(hi) << 32);
    __hip_atomic_store((unsigned long long*)p, pk, __ATOMIC_RELAXED, __HIP_MEMORY_SCOPE_AGENT);
}
__device__ __forceinline__ void st_flag(int* p, int v) {
    (void)__hip_atomic_exchange(p, v, __ATOMIC_RELAXED, __HIP_MEMORY_SCOPE_AGENT);
}
__device__ __forceinline__ void wait_vm0() { asm volatile("s_waitcnt vmcnt(0)" ::: "memory"); }

__device__ __forceinline__ void wait_flags16(int* f, int n, int want, int lane) {
    int it = 0;
    for (;;) {
        bool ok = true;
        for (int i = lane; i < n; i += 64)
            ok &= (__hip_atomic_load(&f[i * FSP], __ATOMIC_RELAXED, __HIP_MEMORY_SCOPE_AGENT) == want);
        if (__all(ok)) break;
        __builtin_amdgcn_s_sleep(8);
        if (++it > (1 << 20)) break;  // hang valve
    }
}

// ================= zx precompute (R9/R10-verified) =================
__global__ void __launch_bounds__(NTHR, 2)
pre_kernel(const float* __restrict__ X, const float* __restrict__ Wih,
           const float* __restrict__ bih, const float* __restrict__ bhh) {
    __shared__ float4 p_x[4096];
    const int w = blockIdx.x, tid = threadIdx.x;
    const int t = w >> 1, half = w & 1;
#pragma unroll
    for (int rep = 0; rep < 16; ++rep) {
        const int idx = rep * 256 + tid;
        const int bl = idx >> 6, c = idx & 63;
        p_x[bl * 64 + (c ^ bl)] =
            *(const float4*)&X[((size_t)(half * 64 + bl) * TSTEPS + t) * INSZ + c * 4];
    }
    __syncthreads();
    const int bl = tid & 63, hf2 = tid >> 6;
    const int b = half * 64 + bl;
    const float4* wih4 = (const float4*)Wih;
    for (int jb4 = 0; jb4 < 16; ++jb4) {
        float a16[16];
#pragma unroll
        for (int i = 0; i < 16; ++i) a16[i] = 0.f;
#pragma unroll 4
        for (int c = 0; c < 64; ++c) {
            const float4 xv = p_x[bl * 64 + (c ^ bl)];
#pragma unroll
            for (int g = 0; g < 4; ++g)
#pragma unroll
                for (int j4 = 0; j4 < 4; ++j4) {
                    const int row = g * HSZ + hf2 * 64 + jb4 * 4 + j4;
                    const float4 wv4 = wih4[(size_t)row * 64 + c];
                    a16[g * 4 + j4] += wv4.x * xv.x + wv4.y * xv.y + wv4.z * xv.z + wv4.w * xv.w;
                }
        }
#pragma unroll
        for (int g = 0; g < 4; ++g)
#pragma unroll
            for (int j4 = 0; j4 < 4; ++j4) {
                const int j = hf2 * 64 + jb4 * 4 + j4;
                const int row = g * HSZ + j;
                g_zx[(((size_t)t * 4 + g) * HSZ + j) * BATCH + b] =
                    a16[g * 4 + j4] + bih[row] + bhh[row];
            }
    }
}

// ================= persistent A/B/C + clock-keeper fillers =================
__global__ void __launch_bounds__(NTHR, 1)
mann_persist(const float* __restrict__ Whh, float* __restrict__ out) {
    __shared__ float4 s_big[8192];   // A: s_h4 (64KB used); B: s_M (128 KB)
    __shared__ float s_aux[1024];    // B: s_h2+s_wr2; C: s_wwc
    __shared__ float s_tr[512];      // A: publish staging [8 j][64 b]
    __shared__ float s_red8[8];
    __shared__ float s_red16[16];
    __shared__ unsigned long long s_redu8[8];

    const int w = blockIdx.x, tid = threadIdx.x;
    const int lane = tid & 63, wv = tid >> 6;

    auto grpsum = [&](float v) -> float {
#pragma unroll
        for (int o = 32; o; o >>= 1) v += __shfl_xor(v, o, 64);
        if (lane == 0) s_red8[wv] = v;
        __syncthreads();
        float r = s_red8[(tid >> 7) * 2] + s_red8[(tid >> 7) * 2 + 1];
        __syncthreads();
        return r;
    };
    auto grpmax = [&](float v) -> float {
#pragma unroll
        for (int o = 32; o; o >>= 1) v = fmaxf(v, __shfl_xor(v, o, 64));
        if (lane == 0) s_red8[wv] = v;
        __syncthreads();
        float r = fmaxf(s_red8[(tid >> 7) * 2], s_red8[(tid >> 7) * 2 + 1]);
        __syncthreads();
        return r;
    };
    auto grpminu = [&](unsigned long long v) -> unsigned long long {
#pragma unroll
        for (int o = 32; o; o >>= 1) {
            unsigned long long o2 = __shfl_xor(v, o, 64);
            v = (o2 < v) ? o2 : v;
        }
        if (lane == 0) s_redu8[wv] = v;
        __syncthreads();
        unsigned long long a = s_redu8[(tid >> 7) * 2], b2 = s_redu8[(tid >> 7) * 2 + 1];
        unsigned long long r = (a < b2) ? a : b2;
        __syncthreads();
        return r;
    };
    auto red256sum4 = [&](float v0, float v1, float v2, float v3, float (&r)[4]) {
#pragma unroll
        for (int o = 32; o; o >>= 1) {
            v0 += __shfl_xor(v0, o, 64);
            v1 += __shfl_xor(v1, o, 64);
            v2 += __shfl_xor(v2, o, 64);
            v3 += __shfl_xor(v3, o, 64);
        }
        if (lane == 0) {
            s_red16[wv * 4 + 0] = v0; s_red16[wv * 4 + 1] = v1;
            s_red16[wv * 4 + 2] = v2; s_red16[wv * 4 + 3] = v3;
        }
        __syncthreads();
#pragma unroll
        for (int k = 0; k < 4; ++k)
            r[k] = (s_red16[0 * 4 + k] + s_red16[1 * 4 + k]) +
                   (s_red16[2 * 4 + k] + s_red16[3 * 4 + k]);
        __syncthreads();
    };

    if (w < NWG_A) {
        // ====== A: h(t) = LSTM(zx(t), h(t-1)); j-partitioned, half-local gather ======
        const int bb = w >> 5, jb = w & 31;
        const int J = jb * 8;
        const int jA = J + wv * 2;
        const int bglob = bb * 64 + lane;
        float4* s_h4 = s_big;
        float creg0 = 0.f, creg1 = 0.f;
        float zxr[8];
#pragma unroll
        for (int g = 0; g < 4; ++g)
#pragma unroll
            for (int jj = 0; jj < 2; ++jj)
                zxr[g * 2 + jj] = g_zx[((size_t)(0 * 4 + g) * HSZ + jA + jj) * BATCH + bglob];

        for (int t = 0; t < TSTEPS; ++t) {
            if (t > 0) {
                if (wv == 0)
                    wait_flags16(g_fA + ((size_t)(t - 1) * NWG_A + bb * 32) * FSP, 32, t, lane);
                __syncthreads();
                asm volatile("" ::: "memory");
#pragma unroll
                for (int rep = 0; rep < 16; ++rep) {
                    const int id = rep * 256 + tid, b = id >> 6, c = id & 63;
                    s_h4[b * 64 + (c ^ (b & 7))] =
                        *(const float4*)&g_hB[((size_t)(t - 1) * BATCH + bb * 64 + b) * HSZ + c * 4];
                }
                __syncthreads();
            }
            float acc[8] = {0.f, 0.f, 0.f, 0.f, 0.f, 0.f, 0.f, 0.f};
            if (t > 0) {
#pragma unroll 8
                for (int c = 0; c < 64; ++c) {
                    const float4 xv = s_h4[lane * 64 + (c ^ (lane & 7))];
#pragma unroll
                    for (int g = 0; g < 4; ++g)
#pragma unroll
                        for (int jj = 0; jj < 2; ++jj) {
                            const float4 w4 =
                                *(const float4*)&Whh[(size_t)(g * HSZ + jA + jj) * HSZ + c * 4];
                            acc[g * 2 + jj] += w4.x * xv.x + w4.y * xv.y + w4.z * xv.z + w4.w * xv.w;
                        }
                }
            }
#pragma unroll
            for (int jj = 0; jj < 2; ++jj) {
                const float z0 = zxr[0 * 2 + jj] + acc[0 * 2 + jj];
                const float z1 = zxr[1 * 2 + jj] + acc[1 * 2 + jj];
                const float z2 = zxr[2 * 2 + jj] + acc[2 * 2 + jj];
                const float z3 = zxr[3 * 2 + jj] + acc[3 * 2 + jj];
                float cr = jj ? creg1 : creg0;
                const float cn = sigf(z1) * cr + sigf(z0) * tanhf(z2);
                const float hn = sigf(z3) * tanhf(cn);
                if (jj) creg1 = cn; else creg0 = cn;
                s_tr[(wv * 2 + jj) * 64 + lane] = hn;
            }
            __syncthreads();
            if (tid < 128) {
                {   // b-major publish
                    const int b = tid >> 1, q = tid & 1;
                    const float v0 = s_tr[(q * 4 + 0) * 64 + b];
                    const float v1 = s_tr[(q * 4 + 1) * 64 + b];
                    const float v2 = s_tr[(q * 4 + 2) * 64 + b];
                    const float v3 = s_tr[(q * 4 + 3) * 64 + b];
                    float* dst = &g_hB[((size_t)t * BATCH + bb * 64 + b) * HSZ + J + q * 4];
                    st_wt2(dst, v0, v1);
                    st_wt2(dst + 2, v2, v3);
                }
                {   // j-major publish
                    const int j = tid >> 4, c = tid & 15;
                    const float v0 = s_tr[j * 64 + c * 4 + 0];
                    const float v1 = s_tr[j * 64 + c * 4 + 1];
                    const float v2 = s_tr[j * 64 + c * 4 + 2];
                    const float v3 = s_tr[j * 64 + c * 4 + 3];
                    float* dst = &g_hT[((size_t)t * HSZ + J + j) * BATCH + bb * 64 + c * 4];
                    st_wt2(dst, v0, v1);
                    st_wt2(dst + 2, v2, v3);
                }
            }
            wait_vm0();
            __syncthreads();
            if (tid == 0) st_flag(&g_fA[((size_t)t * NWG_A + w) * FSP], t + 1);
            if (t + 1 < TSTEPS) {
#pragma unroll
                for (int g = 0; g < 4; ++g)
#pragma unroll
                    for (int jj = 0; jj < 2; ++jj)
                        zxr[g * 2 + jj] =
                            g_zx[((size_t)((t + 1) * 4 + g) * HSZ + jA + jj) * BATCH + bglob];
            }
        }
    } else if (w < NWG_A + NWG_B) {
        // ====== B: read head + output + w_u/w_w; chain publishes BEFORE off-chain work ======
        const int bwg = w - NWG_A;
        const int halfB = bwg >> 5;
        const int grp = tid >> 7, lm = tid & 127;
        const int bB = bwg * 2 + grp;
        float* s_M = (float*)s_big;
        float* s_h2 = s_aux;
        float* s_wr2 = s_aux + 512;
        float wwreg = (lm == 0) ? OMG_C : 0.f;
        float wureg = 0.f;

        for (int t = 0; t < TSTEPS; ++t) {
            if (t > 0) {
                if (wv == 1) wait_flags16(g_fC + (size_t)(t - 1) * NWG_C * FSP, NWG_C, t, lane);
                __syncthreads();
                asm volatile("" ::: "memory");
                float4 mt[32];
                const float4* msrc = (const float4*)&g_M[(size_t)t * MEMN * HSZ];
#pragma unroll
                for (int i = 0; i < 32; ++i) mt[i] = msrc[i * 256 + tid];
                float4* md = (float4*)s_M;
#pragma unroll
                for (int i = 0; i < 32; ++i) md[i * 256 + tid] = mt[i];
            }
            if (wv == 0)
                wait_flags16(g_fA + ((size_t)t * NWG_A + halfB * 32) * FSP, 32, t + 1, lane);
            __syncthreads();
            asm volatile("" ::: "memory");
            s_h2[grp * 256 + lm] = g_hB[((size_t)t * BATCH + bB) * HSZ + lm];
            s_h2[grp * 256 + 128 + lm] = g_hB[((size_t)t * BATCH + bB) * HSZ + 128 + lm];
            __syncthreads();
            const float hv0 = s_h2[grp * 256 + lm], hv1 = s_h2[grp * 256 + lm + 128];
            const float hnorm = sqrtf(grpsum(hv0 * hv0 + hv1 * hv1));
            float sc = 0.f;
            if (t > 0) {
                const float4* mrow = (const float4*)&s_M[(size_t)lm * HSZ];
                const float4* h4 = (const float4*)&s_h2[grp * 256];
                const int sw = lm & 7;
                float a = 0.f;
#pragma unroll 8
                for (int c = 0; c < 64; ++c) {
                    const int ci = c ^ sw;
                    const float4 m4 = mrow[ci], x4 = h4[ci];
                    a += m4.x * x4.x + m4.y * x4.y + m4.z * x4.z + m4.w * x4.w;
                }
                const float mn = g_Mn[(size_t)t * MEMN + lm];
                sc = a / (hnorm * mn + 1e-8f);
            }
            const float mx = grpmax(sc);
            const float ev = expf(sc - mx);
            const float es = grpsum(ev);
            const float wr = ev / es;
            s_wr2[grp * 128 + lm] = wr;
            __syncthreads();
            // ---- chain-critical: wu/ww update + publish + flag ----
            const float un = GAMMA_C * wureg + wr + wwreg;
            const float un2 = grpsum(un * un);
            const float us = 1.0f / fmaxf(sqrtf(un2), 1e-12f);
            const float wun = un * us;
            wureg = wun;
            unsigned long long key =
                (((unsigned long long)__float_as_uint(wun)) << 32) | (unsigned)lm;
            const unsigned long long mk = grpminu(key);
            const int amin = (int)(mk & 0xffffffffu);
            const float wwn = GATE_C * wr + ((lm == amin) ? OMG_C : 0.f);
            wwreg = wwn;
            if (t + 1 < TSTEPS)
                st_wt(&g_wwT[((size_t)(t + 1) * MEMN + lm) * BATCH + bB], wwn);
            wait_vm0();
            __syncthreads();
            if (tid == 0) st_flag(&g_fB[((size_t)t * NWG_B + bwg) * FSP], t + 1);
            // ---- off-chain: read vector + out (drains during next step's waits) ----
            float rd0 = 0.f, rd1 = 0.f;
            if (t > 0) {
#pragma unroll 8
                for (int m = 0; m < 128; ++m) {
                    const float mv = s_M[m * HSZ + tid];
                    rd0 += s_wr2[m] * mv;
                    rd1 += s_wr2[128 + m] * mv;
                }
            }
            float* o0 = out + ((size_t)(bwg * 2) * TSTEPS + t) * 512;
            float* o1 = out + ((size_t)(bwg * 2 + 1) * TSTEPS + t) * 512;
            o0[tid] = s_h2[tid];
            o1[tid] = s_h2[256 + tid];
            o0[256 + tid] = rd0;
            o1[256 + tid] = rd1;
            __syncthreads();  // protect s_M/s_wr2/s_h2 before next iteration's staging
        }
    } else if (w < NWG) {
        // ====== C: M(t+1) = l2norm(M(t) + ww(t)^T h(t)) ======
        const int cwg = w - NWG_A - NWG_B;
        const int m0 = cwg * 4;
        float* s_wwc = s_aux;  // [4][128]
        float mreg[4] = {0.f, 0.f, 0.f, 0.f};

        for (int t = 0; t < TSTEPS - 1; ++t) {
            if (wv == 1 && t > 0)
                wait_flags16(g_fB + (size_t)(t - 1) * NWG_B * FSP, NWG_B, t, lane);
            __syncthreads();
            asm volatile("" ::: "memory");
            {
                const int e0 = tid, e1 = tid + 256;
                float v0, v1;
                if (t > 0) {
                    v0 = g_wwT[((size_t)t * MEMN + m0 + (e0 >> 7)) * BATCH + (e0 & 127)];
                    v1 = g_wwT[((size_t)t * MEMN + m0 + (e1 >> 7)) * BATCH + (e1 & 127)];
                } else {
                    v0 = (m0 + (e0 >> 7) == 0) ? OMG_C : 0.f;
                    v1 = (m0 + (e1 >> 7) == 0) ? OMG_C : 0.f;
                }
                s_wwc[(e0 >> 7) * 128 + (e0 & 127)] = v0;
                s_wwc[(e1 >> 7) * 128 + (e1 & 127)] = v1;
            }
            if (wv == 0) wait_flags16(g_fA + (size_t)t * NWG_A * FSP, NWG_A, t + 1, lane);
            __syncthreads();
            asm volatile("" ::: "memory");
            float4 hb[32];
            const float4* ht4 = (const float4*)&g_hT[((size_t)t * HSZ + tid) * BATCH];
#pragma unroll
            for (int q = 0; q < 32; ++q) hb[q] = ht4[q];
            float macc[4];
#pragma unroll
            for (int mi = 0; mi < 4; ++mi) macc[mi] = mreg[mi];
#pragma unroll
            for (int b4 = 0; b4 < 32; ++b4) {
                const float4 hv4 = hb[b4];
#pragma unroll
                for (int mi = 0; mi < 4; ++mi) {
                    const float* wc = &s_wwc[mi * 128 + b4 * 4];
                    macc[mi] += wc[0] * hv4.x + wc[1] * hv4.y + wc[2] * hv4.z + wc[3] * hv4.w;
                }
            }
            float nr[4];
            red256sum4(macc[0] * macc[0], macc[1] * macc[1],
                       macc[2] * macc[2], macc[3] * macc[3], nr);
#pragma unroll
            for (int mi = 0; mi < 4; ++mi) {
                const float nrm = sqrtf(nr[mi]);
                const float scale = 1.0f / fmaxf(nrm, 1e-12f);
                const float vo = macc[mi] * scale;
                mreg[mi] = vo;
                st_wt(&g_M[((size_t)(t + 1) * MEMN + m0 + mi) * HSZ + tid], vo);
                if (tid == 0) st_wt(&g_Mn[(size_t)(t + 1) * MEMN + m0 + mi], nrm * scale);
            }
            wait_vm0();
            __syncthreads();
            if (tid == 0) st_flag(&g_fC[((size_t)t * NWG_C + cwg) * FSP], t + 1);
        }
    } else {
        // ====== F: clock-keeper filler — holds SCLK up; exits when B finishes ======
        const int slot = (w - NWG) & (NWG_B - 1);
        int* fexit = &g_fB[((size_t)(TSTEPS - 1) * NWG_B + slot) * FSP];
        float a0 = 1.0f + 1e-6f * (float)tid, a1 = a0 + 0.25f;
        float a2 = a0 + 0.5f, a3 = a0 + 0.75f;
        const float mm = 0.99999988f;
        int it = 0;
        for (;;) {
#pragma unroll 32
            for (int i = 0; i < 2048; ++i) {
                a0 = fmaf(a0, mm, 1e-7f);
                a1 = fmaf(a1, mm, 2e-7f);
                a2 = fmaf(a2, mm, 3e-7f);
                a3 = fmaf(a3, mm, 4e-7f);
            }
            if (__hip_atomic_load(fexit, __ATOMIC_RELAXED, __HIP_MEMORY_SCOPE_AGENT) == TSTEPS)
                break;
            if (++it > (1 << 16)) break;  // hang valve (~0.5 s cap)
        }
        asm volatile("" :: "v"(a0), "v"(a1), "v"(a2), "v"(a3));
    }
}

extern "C" void kernel_launch(void* const* d_in, const int* in_sizes, int n_in,
                              void* d_out, int out_size, void* d_ws, size_t ws_size,
                              hipStream_t stream) {
    const float* X   = (const float*)d_in[0];
    const float* Wih = (const float*)d_in[1];
    const float* Whh = (const float*)d_in[2];
    const float* bih = (const float*)d_in[3];
    const float* bhh = (const float*)d_in[4];
    float* out = (float*)d_out;
    (void)in_sizes; (void)n_in; (void)out_size; (void)d_ws; (void)ws_size;

    hipLaunchKernelGGL(reset_ctrl_kernel, dim3(1024), dim3(256), 0, stream);
    hipLaunchKernelGGL(pre_kernel, dim3(2048), dim3(NTHR), 0, stream, X, Wih, bih, bhh);
    hipLaunchKernelGGL(mann_persist, dim3(NWG_TOT), dim3(NTHR), 0, stream, Whh, out);
}